// Round 13
// baseline (23.864 us; speedup 1.0000x reference)
//
#include <hip/hip_runtime.h>

#define BATCH 2048
#define IND   256
#define OUTD  256

typedef __attribute__((ext_vector_type(8))) short bf16x8;
typedef __attribute__((ext_vector_type(4))) float f32x4;

__device__ __forceinline__ ushort f2bf(float f) {
    uint u = __builtin_bit_cast(uint, f);
    u += 0x7fffu + ((u >> 16) & 1u);          // RNE
    return (ushort)(u >> 16);
}
__device__ __forceinline__ uint pack2(float lo, float hi) {
    return (uint)f2bf(lo) | ((uint)f2bf(hi) << 16);
}

// ---------------- ws layout (fallback paths only) ----------------
#define BIASOFF (1u << 20)                 // W: [0, 1MB)
#define FOFF    ((1u << 20) + 4096)        // F: 8MB
#define WS_NEED ((size_t)FOFF + (size_t)IND * BATCH * 16)

// dynamic LDS layout for kan_single
#define WL_B    131072                      // 256i x 32o uint4 packs
#define RED_B   24576                       // [2][3][4][256] f32
#define BIASP_B 2048                        // [16][32] f32
#define LDSB    (WL_B + RED_B + BIASP_B + 128)

// features for one x value: [silu, B0..B6] (c7 folded: B7 = 1 - sum -> bias)
__device__ __forceinline__ uint4 feat_pack(float xv) {
    const float u = (xv + 1.0f) * 2.5f;
    float cif = floorf(u);
    cif = fminf(fmaxf(cif, 0.0f), 4.0f);
    const int ci = (int)cif;
    const float f = u - cif, mf = 1.0f - f;
    const float f2 = f * f, f3 = f2 * f;
    const float k6 = 1.0f / 6.0f;
    const float w0 = mf * mf * mf * k6;
    const float w1 = (3.0f * f3 - 6.0f * f2 + 4.0f) * k6;
    const float w3 = f3 * k6;
    const float w2 = 1.0f - w0 - w1 - w3;
    const float sg = __fdividef(xv, 1.0f + __expf(-xv));
    const float B0 = (ci == 0) ? w0 : 0.f;
    const float B1 = (ci == 1) ? w0 : (ci == 0) ? w1 : 0.f;
    const float B2 = (ci == 2) ? w0 : (ci == 1) ? w1 : (ci == 0) ? w2 : 0.f;
    const float B3 = (ci == 3) ? w0 : (ci == 2) ? w1 : (ci == 1) ? w2 : (ci == 0) ? w3 : 0.f;
    const float B4 = (ci == 4) ? w0 : (ci == 3) ? w1 : (ci == 2) ? w2 : (ci == 1) ? w3 : 0.f;
    const float B5 = (ci == 4) ? w1 : (ci == 3) ? w2 : (ci == 2) ? w3 : 0.f;
    const float B6 = (ci == 4) ? w2 : (ci == 3) ? w3 : 0.f;
    uint4 v;
    v.x = pack2(sg, B0); v.y = pack2(B1, B2);
    v.z = pack2(B3, B4); v.w = pack2(B5, B6);
    return v;
}

__device__ __forceinline__ uint4 wpack(float m, float b, float sp,
                                       float4 c0, float4 c1, float* c7s) {
    const float wb = m * b, wsp = m * sp;
    const float c7 = c1.w;
    *c7s += wsp * c7;
    uint4 w;
    w.x = pack2(wb,                wsp * (c0.x - c7));
    w.y = pack2(wsp * (c0.y - c7), wsp * (c0.z - c7));
    w.z = pack2(wsp * (c0.w - c7), wsp * (c1.x - c7));
    w.w = pack2(wsp * (c1.y - c7), wsp * (c1.z - c7));
    return w;
}

// ============ SINGLE-DISPATCH kernel ============
// 256 blocks (1/CU) x 512 threads. Block tile 64M x 32N, full K.
// o-tile = bid&7 (XCD-pinned: 360KB coef slice L2-resident), m-tile = bid>>3.
// Prologue: block computes its own W-slice (256i x 32o packs) into XOR-swizzled LDS
//           (+ bias via c7 partition-of-unity fold) — no global W, no second kernel.
// K-loop (no barriers): 8 waves = kq(4) x mh(2), wave tile 32x32 = 2x2 frags.
//   Per k-step: 2 feat_packs (A, from per-lane x loads; each (b,i) once per block),
//   2 ds_read_b128 (B), 4 MFMA, 1-deep prefetch.
// Epilogue: 4-way kq-reduce in LDS + bias + store.
__global__ __launch_bounds__(512, 1) void kan_single(
    const float* __restrict__ x, const float* __restrict__ coef,
    const float* __restrict__ sb, const float* __restrict__ ss,
    const float* __restrict__ mask, float* __restrict__ out)
{
    extern __shared__ char lds[];
    uint4* Wl    = (uint4*)lds;                         // [256][32], slot ^= i&7
    float* red   = (float*)(lds + WL_B);                // [2][3][4][256]
    float* biasp = (float*)(lds + WL_B + RED_B);        // [16][32]
    float* biasf = (float*)(lds + WL_B + RED_B + BIASP_B); // [32]

    const int tid = threadIdx.x;
    const int bid = blockIdx.x;
    const int o0  = (bid & 7) * 32;
    const int b0m = (bid >> 3) * 64;

    // ---- prologue: W-slice + bias partials ----
    {
        const int o = tid & 31, ig = tid >> 5;          // ig 0..15
        const int og = o0 + o;
        float c7s = 0.f;
#pragma unroll 4
        for (int ii = 0; ii < 16; ++ii) {
            const int i  = ig * 16 + ii;
            const int io = i * OUTD + og;
            const float4* cp = reinterpret_cast<const float4*>(coef + (size_t)io * 8);
            const uint4 w = wpack(mask[io], sb[io], ss[io], cp[0], cp[1], &c7s);
            Wl[i * 32 + (o ^ (i & 7))] = w;
        }
        biasp[ig * 32 + o] = c7s;
    }
    __syncthreads();
    if (tid < 32) {
        float s = 0.f;
#pragma unroll
        for (int k = 0; k < 16; ++k) s += biasp[k * 32 + tid];
        biasf[tid] = s;
    }
    __syncthreads();

    // ---- K-loop ----
    const int lane = tid & 63, wid = tid >> 6;
    const int mh = wid & 1, kq = wid >> 1;              // kq 0..3
    const int r = lane & 15, g = lane >> 4;
    const int rowA0 = b0m + mh * 32 + r;                // mf=0 row
    const int rowA1 = rowA0 + 16;                       // mf=1 row

    f32x4 acc[2][2] = {};

    int igc = kq * 64 + g;
    float xa0 = x[(size_t)rowA0 * IND + igc];
    float xa1 = x[(size_t)rowA1 * IND + igc];
    bf16x8 bb0 = __builtin_bit_cast(bf16x8, Wl[igc * 32 + (r ^ (igc & 7))]);
    bf16x8 bb1 = __builtin_bit_cast(bf16x8, Wl[igc * 32 + ((16 + r) ^ (igc & 7))]);

#pragma unroll
    for (int t = 0; t < 16; ++t) {
        float xn0 = 0.f, xn1 = 0.f;
        bf16x8 bn0 = {}, bn1 = {};
        if (t < 15) {
            const int ign = kq * 64 + (t + 1) * 4 + g;
            xn0 = x[(size_t)rowA0 * IND + ign];
            xn1 = x[(size_t)rowA1 * IND + ign];
            bn0 = __builtin_bit_cast(bf16x8, Wl[ign * 32 + (r ^ (ign & 7))]);
            bn1 = __builtin_bit_cast(bf16x8, Wl[ign * 32 + ((16 + r) ^ (ign & 7))]);
        }
        const bf16x8 a0 = __builtin_bit_cast(bf16x8, feat_pack(xa0));
        const bf16x8 a1 = __builtin_bit_cast(bf16x8, feat_pack(xa1));

        acc[0][0] = __builtin_amdgcn_mfma_f32_16x16x32_bf16(a0, bb0, acc[0][0], 0, 0, 0);
        acc[0][1] = __builtin_amdgcn_mfma_f32_16x16x32_bf16(a0, bb1, acc[0][1], 0, 0, 0);
        acc[1][0] = __builtin_amdgcn_mfma_f32_16x16x32_bf16(a1, bb0, acc[1][0], 0, 0, 0);
        acc[1][1] = __builtin_amdgcn_mfma_f32_16x16x32_bf16(a1, bb1, acc[1][1], 0, 0, 0);

        xa0 = xn0; xa1 = xn1; bb0 = bn0; bb1 = bn1;
    }

    // ---- epilogue: 4-way kq-reduce per mh, add bias, store ----
    __syncthreads();
    if (kq > 0) {
        float* dst = red + (size_t)(mh * 3 + kq - 1) * 1024;
#pragma unroll
        for (int mf = 0; mf < 2; ++mf)
#pragma unroll
            for (int nf = 0; nf < 2; ++nf)
                *reinterpret_cast<f32x4*>(dst + (mf * 2 + nf) * 256 + lane * 4) = acc[mf][nf];
    }
    __syncthreads();
    if (kq == 0) {
#pragma unroll
        for (int mf = 0; mf < 2; ++mf)
#pragma unroll
            for (int nf = 0; nf < 2; ++nf) {
                f32x4 s = acc[mf][nf];
                const int sl = (mf * 2 + nf) * 256 + lane * 4;
#pragma unroll
                for (int kk = 0; kk < 3; ++kk) {
                    const f32x4 v = *reinterpret_cast<const f32x4*>(
                        red + (size_t)(mh * 3 + kk) * 1024 + sl);
                    s.x += v.x; s.y += v.y; s.z += v.z; s.w += v.w;
                }
                const int col  = o0 + nf * 16 + r;
                const int row0 = b0m + mh * 32 + mf * 16 + g * 4;
                const float bv = biasf[nf * 16 + r];
#pragma unroll
                for (int e = 0; e < 4; ++e)
                    out[(size_t)(row0 + e) * OUTD + col] = s[e] + bv;
            }
    }
}

// ============ fallback A: R12 two-kernel path (proven 18.75µs) ============
__global__ __launch_bounds__(256) void kan_prep(
    const float* __restrict__ x, const float* __restrict__ coef,
    const float* __restrict__ sb, const float* __restrict__ ss,
    const float* __restrict__ mask,
    uint4* __restrict__ W, float* __restrict__ bias, uint4* __restrict__ F)
{
    const int bid = blockIdx.x, tid = threadIdx.x;
    __shared__ float xt[4 * 260];
    __shared__ float part[32][8];

    const int b0 = (bid & 7) * 256 + (bid >> 3) * 4;
    {
        const int row = tid >> 6, c4 = (tid & 63) * 4;
        const float4 v = *reinterpret_cast<const float4*>(
            x + (size_t)(b0 + row) * IND + c4);
        xt[row * 260 + c4 + 0] = v.x;
        xt[row * 260 + c4 + 1] = v.y;
        xt[row * 260 + c4 + 2] = v.z;
        xt[row * 260 + c4 + 3] = v.w;
    }
    if (tid < 128) {
        const int i = bid >> 1, o = (bid & 1) * 128 + tid;
        const int io = i * OUTD + o;
        float c7s = 0.f;
        const float4* cp = reinterpret_cast<const float4*>(coef + (size_t)io * 8);
        W[io] = wpack(mask[io], sb[io], ss[io], cp[0], cp[1], &c7s);
    }
    __syncthreads();
#pragma unroll
    for (int p = 0; p < 4; ++p) {
        const int q = p * 256 + tid;
        const int i = q >> 2, b = q & 3;
        F[(size_t)i * BATCH + b0 + b] = feat_pack(xt[b * 260 + i]);
    }
    if (bid >= 480) {
        const int o0 = (bid - 480) * 8;
        const int ol = tid & 7, ig = tid >> 3;
        float s = 0.f;
#pragma unroll
        for (int ii = 0; ii < 8; ++ii) {
            const int i = ig * 8 + ii;
            const int io = i * OUTD + o0 + ol;
            s += mask[io] * ss[io] * coef[(size_t)io * 8 + 7];
        }
        part[ig][ol] = s;
        __syncthreads();
        if (tid < 8) {
            float acc = 0.f;
#pragma unroll
            for (int g2 = 0; g2 < 32; ++g2) acc += part[g2][tid];
            bias[o0 + tid] = acc;
        }
    }
}

__global__ __launch_bounds__(512, 4) void kan_gemm(
    const uint4* __restrict__ F, const uint4* __restrict__ W,
    const float* __restrict__ bias, float* __restrict__ out)
{
    const int tid  = threadIdx.x;
    const int lane = tid & 63, wid = tid >> 6;
    const int mh = wid & 1, kq = wid >> 1;
    const int r = lane & 15, g = lane >> 4;
    const int bid = blockIdx.x;
    const int xcd = bid & 7, rest = bid >> 3;
    const int b0 = (xcd * 8 + (rest >> 3)) * 32;
    const int o0 = (rest & 7) * 32;

    const uint4* pA = F + (size_t)(kq * 64 + g) * BATCH + b0 + mh * 16 + r;
    const uint4* pB = W + (size_t)(kq * 64 + g) * OUTD + o0 + r;

    f32x4 acc[2] = {};
    bf16x8 a_0, b0_0, b1_0;
    bf16x8 a_1, b0_1, b1_1;
    bf16x8 a_2, b0_2, b1_2;
    bf16x8 a_3, b0_3, b1_3;

#define LDS_(s, t)                                                                     \
    {                                                                                  \
        a_##s  = *reinterpret_cast<const bf16x8*>(pA + (size_t)(4 * (t)) * BATCH);     \
        b0_##s = *reinterpret_cast<const bf16x8*>(pB + (size_t)(4 * (t)) * OUTD);      \
        b1_##s = *reinterpret_cast<const bf16x8*>(pB + (size_t)(4 * (t)) * OUTD + 16); \
    }
#define MM_(s)                                                                         \
    {                                                                                  \
        acc[0] = __builtin_amdgcn_mfma_f32_16x16x32_bf16(a_##s, b0_##s, acc[0], 0, 0, 0); \
        acc[1] = __builtin_amdgcn_mfma_f32_16x16x32_bf16(a_##s, b1_##s, acc[1], 0, 0, 0); \
    }

    LDS_(0, 0)  LDS_(1, 1)  LDS_(2, 2)  LDS_(3, 3)
    MM_(0) LDS_(0, 4)   MM_(1) LDS_(1, 5)   MM_(2) LDS_(2, 6)   MM_(3) LDS_(3, 7)
    MM_(0) LDS_(0, 8)   MM_(1) LDS_(1, 9)   MM_(2) LDS_(2, 10)  MM_(3) LDS_(3, 11)
    MM_(0) LDS_(0, 12)  MM_(1) LDS_(1, 13)  MM_(2) LDS_(2, 14)  MM_(3) LDS_(3, 15)
    MM_(0) MM_(1) MM_(2) MM_(3)
#undef LDS_
#undef MM_

    __shared__ float red2[2][3][512];
    if (kq > 0) {
        float* dst = &red2[mh][kq - 1][0];
#pragma unroll
        for (int nf = 0; nf < 2; ++nf)
            *reinterpret_cast<f32x4*>(dst + nf * 256 + lane * 4) = acc[nf];
    }
    __syncthreads();
    if (kq == 0) {
#pragma unroll
        for (int nf = 0; nf < 2; ++nf) {
            f32x4 s = acc[nf];
            const int sl = nf * 256 + lane * 4;
#pragma unroll
            for (int kk = 0; kk < 3; ++kk) {
                const f32x4 v = *reinterpret_cast<const f32x4*>(&red2[mh][kk][0] + sl);
                s.x += v.x; s.y += v.y; s.z += v.z; s.w += v.w;
            }
            const int col  = o0 + nf * 16 + r;
            const int row0 = b0 + mh * 16 + g * 4;
            const float bv = bias[col];
#pragma unroll
            for (int e = 0; e < 4; ++e)
                out[(size_t)(row0 + e) * OUTD + col] = s[e] + bv;
        }
    }
}

// ============ fallback B: self-contained fused (no ws) ============
#define KPI  16
#define IPC  8
#define KC   (IPC * KPI)

__global__ __launch_bounds__(256, 2) void kan_mfma(
    const float* __restrict__ x, const float* __restrict__ coef,
    const float* __restrict__ scale_base, const float* __restrict__ scale_sp,
    const float* __restrict__ mask, float* __restrict__ out)
{
    const int tid = threadIdx.x;
    const int b0 = blockIdx.x * 32, o0 = blockIdx.y * 32;
    __shared__ uint Fa[32 * KC / 2];
    __shared__ uint Wt2[32 * KC / 2];
    for (int j = tid; j < 32 * KC / 2; j += 256) { Fa[j] = 0u; Wt2[j] = 0u; }
    const int lane = tid & 63, wid = tid >> 6;
    const int wmv = (wid >> 1) * 16, wnv = (wid & 1) * 16;
    f32x4 acc = {0.f, 0.f, 0.f, 0.f};
    const int fb = tid & 31, il = tid >> 5;
    for (int ic = 0; ic < IND / IPC; ++ic) {
        const int i = ic * IPC + il;
        __syncthreads();
        {
            const uint4 fp = feat_pack(x[(b0 + fb) * IND + i]);
            const int base = fb * (KC / 2) + il * (KPI / 2);
            const int sw = (fb & 7) << 2;
            Fa[(base + 0) ^ sw] = fp.x; Fa[(base + 1) ^ sw] = fp.y;
            Fa[(base + 2) ^ sw] = fp.z; Fa[(base + 3) ^ sw] = fp.w;
            ((ushort*)Fa)[2 * ((base + 4) ^ sw)] = 0;
        }
        {
            const int io = i * OUTD + o0 + fb;
            float c7s = 0.f;
            const float4* cp = reinterpret_cast<const float4*>(coef + (size_t)io * 8);
            const uint4 w = wpack(mask[io], scale_base[io], scale_sp[io], cp[0], cp[1], &c7s);
            const int base = fb * (KC / 2) + il * (KPI / 2);
            const int sw = (fb & 7) << 2;
            Wt2[(base + 0) ^ sw] = w.x;
            Wt2[(base + 1) ^ sw] = w.y;
            Wt2[(base + 2) ^ sw] = w.z;
            Wt2[(base + 3) ^ sw] = w.w;
            ((ushort*)Wt2)[2 * ((base + 4) ^ sw)] = 0;
        }
        __syncthreads();
        {
            const ushort* fs = (const ushort*)Fa;
            const ushort* wsd = (const ushort*)Wt2;
            const int ar = wmv + (lane & 15), br = wnv + (lane & 15);
            const int kg = (lane >> 4) * 8;
#pragma unroll
            for (int ksi = 0; ksi < 4; ++ksi) {
                const int ka = ksi * 32 + kg;
                const int ia = (ar * KC + ka) ^ ((ar & 7) << 3);
                const int ib = (br * KC + ka) ^ ((br & 7) << 3);
                bf16x8 a = *reinterpret_cast<const bf16x8*>(fs + ia);
                bf16x8 b = *reinterpret_cast<const bf16x8*>(wsd + ib);
                acc = __builtin_amdgcn_mfma_f32_16x16x32_bf16(a, b, acc, 0, 0, 0);
            }
        }
    }
    const int col = o0 + wnv + (lane & 15);
    const int row0 = b0 + wmv + ((lane >> 4) << 2);
    float bv = 0.f;
    for (int i = 0; i < IND; ++i) {
        const int io = i * OUTD + col;
        bv += mask[io] * scale_sp[io] * coef[(size_t)io * 8 + 7];
    }
#pragma unroll
    for (int rr = 0; rr < 4; ++rr)
        out[(size_t)(row0 + rr) * OUTD + col] = acc[rr] + bv;
}

extern "C" void kernel_launch(void* const* d_in, const int* in_sizes, int n_in,
                              void* d_out, int out_size, void* d_ws, size_t ws_size,
                              hipStream_t stream) {
    const float* x          = (const float*)d_in[0];
    const float* coef       = (const float*)d_in[2];
    const float* scale_base = (const float*)d_in[3];
    const float* scale_sp   = (const float*)d_in[4];
    const float* mask       = (const float*)d_in[5];
    float* out = (float*)d_out;

    hipError_t e = hipFuncSetAttribute(
        (const void*)kan_single, hipFuncAttributeMaxDynamicSharedMemorySize, LDSB);
    if (e == hipSuccess) {
        kan_single<<<256, 512, LDSB, stream>>>(x, coef, scale_base, scale_sp, mask, out);
    } else if (ws_size >= WS_NEED) {
        uint4* W    = (uint4*)d_ws;
        float* bias = (float*)((char*)d_ws + BIASOFF);
        uint4* F    = (uint4*)((char*)d_ws + FOFF);
        kan_prep<<<512, 256, 0, stream>>>(x, coef, scale_base, scale_sp, mask, W, bias, F);
        kan_gemm<<<512, 512, 0, stream>>>(F, W, bias, out);
    } else {
        kan_mfma<<<dim3(BATCH / 32, OUTD / 32), 256, 0, stream>>>(
            x, coef, scale_base, scale_sp, mask, out);
    }
}

// Round 14
// 17.387 us; speedup vs baseline: 1.3725x; 1.3725x over previous
//
#include <hip/hip_runtime.h>

#define BATCH 2048
#define IND   256
#define OUTD  256

typedef __attribute__((ext_vector_type(8))) short bf16x8;
typedef __attribute__((ext_vector_type(4))) float f32x4;

__device__ __forceinline__ ushort f2bf(float f) {
    uint u = __builtin_bit_cast(uint, f);
    u += 0x7fffu + ((u >> 16) & 1u);          // RNE
    return (ushort)(u >> 16);
}
__device__ __forceinline__ uint pack2(float lo, float hi) {
    return (uint)f2bf(lo) | ((uint)f2bf(hi) << 16);
}

// ---------------- ws layout ----------------
#define BIASOFF (1u << 20)                 // W: [0, 1MB)
#define FOFF    ((1u << 20) + 4096)        // F: 8MB
#define WS_NEED ((size_t)FOFF + (size_t)IND * BATCH * 16)

#define LDSB2   131072                      // kan_gemm dynamic LDS: Wl [256][32] uint4

// features for one x value: [silu, B0..B6] (c7 folded: B7 = 1 - sum -> bias)
__device__ __forceinline__ uint4 feat_pack(float xv) {
    const float u = (xv + 1.0f) * 2.5f;
    float cif = floorf(u);
    cif = fminf(fmaxf(cif, 0.0f), 4.0f);
    const int ci = (int)cif;
    const float f = u - cif, mf = 1.0f - f;
    const float f2 = f * f, f3 = f2 * f;
    const float k6 = 1.0f / 6.0f;
    const float w0 = mf * mf * mf * k6;
    const float w1 = (3.0f * f3 - 6.0f * f2 + 4.0f) * k6;
    const float w3 = f3 * k6;
    const float w2 = 1.0f - w0 - w1 - w3;
    const float sg = __fdividef(xv, 1.0f + __expf(-xv));
    const float B0 = (ci == 0) ? w0 : 0.f;
    const float B1 = (ci == 1) ? w0 : (ci == 0) ? w1 : 0.f;
    const float B2 = (ci == 2) ? w0 : (ci == 1) ? w1 : (ci == 0) ? w2 : 0.f;
    const float B3 = (ci == 3) ? w0 : (ci == 2) ? w1 : (ci == 1) ? w2 : (ci == 0) ? w3 : 0.f;
    const float B4 = (ci == 4) ? w0 : (ci == 3) ? w1 : (ci == 2) ? w2 : (ci == 1) ? w3 : 0.f;
    const float B5 = (ci == 4) ? w1 : (ci == 3) ? w2 : (ci == 2) ? w3 : 0.f;
    const float B6 = (ci == 4) ? w2 : (ci == 3) ? w3 : 0.f;
    uint4 v;
    v.x = pack2(sg, B0); v.y = pack2(B1, B2);
    v.z = pack2(B3, B4); v.w = pack2(B5, B6);
    return v;
}

__device__ __forceinline__ uint4 wpack(float m, float b, float sp,
                                       float4 c0, float4 c1) {
    const float wb = m * b, wsp = m * sp;
    const float c7 = c1.w;
    uint4 w;
    w.x = pack2(wb,                wsp * (c0.x - c7));
    w.y = pack2(wsp * (c0.y - c7), wsp * (c0.z - c7));
    w.z = pack2(wsp * (c0.w - c7), wsp * (c1.x - c7));
    w.w = pack2(wsp * (c1.y - c7), wsp * (c1.z - c7));
    return w;
}

// ============ kernel 1: prep (R8 verbatim — proven) ============
__global__ __launch_bounds__(256) void kan_prep(
    const float* __restrict__ x, const float* __restrict__ coef,
    const float* __restrict__ sb, const float* __restrict__ ss,
    const float* __restrict__ mask,
    uint4* __restrict__ W, float* __restrict__ bias, uint4* __restrict__ F)
{
    const int bid = blockIdx.x, tid = threadIdx.x;
    __shared__ float xt[4 * 260];
    __shared__ float part[32][8];

    const int b0 = (bid & 7) * 256 + (bid >> 3) * 4;
    {
        const int row = tid >> 6, c4 = (tid & 63) * 4;
        const float4 v = *reinterpret_cast<const float4*>(
            x + (size_t)(b0 + row) * IND + c4);
        xt[row * 260 + c4 + 0] = v.x;
        xt[row * 260 + c4 + 1] = v.y;
        xt[row * 260 + c4 + 2] = v.z;
        xt[row * 260 + c4 + 3] = v.w;
    }
    if (tid < 128) {
        const int i = bid >> 1, o = (bid & 1) * 128 + tid;
        const int io = i * OUTD + o;
        const float4* cp = reinterpret_cast<const float4*>(coef + (size_t)io * 8);
        W[io] = wpack(mask[io], sb[io], ss[io], cp[0], cp[1]);
    }
    __syncthreads();
#pragma unroll
    for (int p = 0; p < 4; ++p) {
        const int q = p * 256 + tid;
        const int i = q >> 2, b = q & 3;
        F[(size_t)i * BATCH + b0 + b] = feat_pack(xt[b * 260 + i]);
    }
    if (bid >= 480) {
        const int o0 = (bid - 480) * 8;
        const int ol = tid & 7, ig = tid >> 3;
        float s = 0.f;
#pragma unroll
        for (int ii = 0; ii < 8; ++ii) {
            const int i = ig * 8 + ii;
            const int io = i * OUTD + o0 + ol;
            s += mask[io] * ss[io] * coef[(size_t)io * 8 + 7];
        }
        part[ig][ol] = s;
        __syncthreads();
        if (tid < 8) {
            float acc = 0.f;
#pragma unroll
            for (int g2 = 0; g2 < 32; ++g2) acc += part[g2][tid];
            bias[o0 + tid] = acc;
        }
    }
}

// ============ kernel 2: GEMM with whole-K B-tile in LDS ============
// 256 blocks x 512 threads (1 block/CU). Block tile 64M x 32N, full K.
// xcd = bid&7: b0 = xcd*256 + ((bid>>3)&3)*64 (XCD-local F slice), o0 = (bid>>5)*32.
// Prologue: bulk-copy this block's full-K B-slice (256i x 32o = 128KB) from W into
//   XOR-swizzled LDS once (coalesced; latency amortized). K-loop (no barriers):
//   8 waves = kq(4) x mh(2), wave tile 32x32 = 2x2 frags; per step 2 XCD-local A-loads
//   (depth-2 prefetch) + 2 conflict-free ds_read_b128 + 4 MFMA. Zero global B traffic.
// Epilogue: 4-way kq-reduce (reuses LDS) + bias + store.
__global__ __launch_bounds__(512, 1) void kan_gemm(
    const uint4* __restrict__ F, const uint4* __restrict__ W,
    const float* __restrict__ bias, float* __restrict__ out)
{
    extern __shared__ uint4 Wl[];                     // [256][32], slot ^= i&7

    const int tid  = threadIdx.x;
    const int lane = tid & 63, wid = tid >> 6;
    const int mh = wid & 1, kq = wid >> 1;            // kq 0..3
    const int r = lane & 15, g = lane >> 4;
    const int bid = blockIdx.x;
    const int xcd = bid & 7;
    const int b0 = xcd * 256 + ((bid >> 3) & 3) * 64; // XCD-local m-tile
    const int o0 = (bid >> 5) * 32;

    // ---- prologue: fill B LDS tile (16 packs/thread, coalesced 512B runs) ----
#pragma unroll
    for (int p = 0; p < 16; ++p) {
        const int s = p * 512 + tid;                  // 0..8191
        const int i = s >> 5, o = s & 31;
        Wl[i * 32 + (o ^ (i & 7))] = W[(size_t)i * OUTD + o0 + o];
    }
    __syncthreads();

    // ---- K-loop: 16 steps, depth-2 A prefetch, B from LDS ----
    const int rowA0 = b0 + mh * 32 + r;
    f32x4 acc[2][2] = {};

    const uint4* pA = F + (size_t)(kq * 64 + g) * BATCH + rowA0;
    bf16x8 aC0 = *reinterpret_cast<const bf16x8*>(pA);
    bf16x8 aC1 = *reinterpret_cast<const bf16x8*>(pA + 16);
    bf16x8 aN0, aN1;

#pragma unroll
    for (int t = 0; t < 16; ++t) {
        const int i = kq * 64 + t * 4 + g;
        if (t < 15) {
            const uint4* pn = F + (size_t)(i + 4) * BATCH + rowA0;
            aN0 = *reinterpret_cast<const bf16x8*>(pn);
            aN1 = *reinterpret_cast<const bf16x8*>(pn + 16);
        }
        const bf16x8 bb0 = __builtin_bit_cast(bf16x8, Wl[i * 32 + (r ^ (i & 7))]);
        const bf16x8 bb1 = __builtin_bit_cast(bf16x8, Wl[i * 32 + ((16 + r) ^ (i & 7))]);

        acc[0][0] = __builtin_amdgcn_mfma_f32_16x16x32_bf16(aC0, bb0, acc[0][0], 0, 0, 0);
        acc[0][1] = __builtin_amdgcn_mfma_f32_16x16x32_bf16(aC0, bb1, acc[0][1], 0, 0, 0);
        acc[1][0] = __builtin_amdgcn_mfma_f32_16x16x32_bf16(aC1, bb0, acc[1][0], 0, 0, 0);
        acc[1][1] = __builtin_amdgcn_mfma_f32_16x16x32_bf16(aC1, bb1, acc[1][1], 0, 0, 0);

        aC0 = aN0; aC1 = aN1;
    }

    // ---- epilogue: 4-way kq-reduce per mh (reuse Wl), add bias, store ----
    __syncthreads();
    float* red = (float*)Wl;                          // [2][3][4][256] = 24KB
    if (kq > 0) {
        float* dst = red + (size_t)(mh * 3 + kq - 1) * 1024;
#pragma unroll
        for (int mf = 0; mf < 2; ++mf)
#pragma unroll
            for (int nf = 0; nf < 2; ++nf)
                *reinterpret_cast<f32x4*>(dst + (mf * 2 + nf) * 256 + lane * 4) = acc[mf][nf];
    }
    __syncthreads();
    if (kq == 0) {
#pragma unroll
        for (int mf = 0; mf < 2; ++mf)
#pragma unroll
            for (int nf = 0; nf < 2; ++nf) {
                f32x4 s = acc[mf][nf];
                const int sl = (mf * 2 + nf) * 256 + lane * 4;
#pragma unroll
                for (int kk = 0; kk < 3; ++kk) {
                    const f32x4 v = *reinterpret_cast<const f32x4*>(
                        red + (size_t)(mh * 3 + kk) * 1024 + sl);
                    s.x += v.x; s.y += v.y; s.z += v.z; s.w += v.w;
                }
                const int col  = o0 + nf * 16 + r;
                const int row0 = b0 + mh * 32 + mf * 16 + g * 4;
                const float bv = bias[col];
#pragma unroll
                for (int e = 0; e < 4; ++e)
                    out[(size_t)(row0 + e) * OUTD + col] = s[e] + bv;
            }
    }
}

// ============ fallback: self-contained fused (no ws) ============
#define KPI  16
#define IPC  8
#define KC   (IPC * KPI)

__global__ __launch_bounds__(256, 2) void kan_mfma(
    const float* __restrict__ x, const float* __restrict__ coef,
    const float* __restrict__ scale_base, const float* __restrict__ scale_sp,
    const float* __restrict__ mask, float* __restrict__ out)
{
    const int tid = threadIdx.x;
    const int b0 = blockIdx.x * 32, o0 = blockIdx.y * 32;
    __shared__ uint Fa[32 * KC / 2];
    __shared__ uint Wt2[32 * KC / 2];
    for (int j = tid; j < 32 * KC / 2; j += 256) { Fa[j] = 0u; Wt2[j] = 0u; }
    const int lane = tid & 63, wid = tid >> 6;
    const int wmv = (wid >> 1) * 16, wnv = (wid & 1) * 16;
    f32x4 acc = {0.f, 0.f, 0.f, 0.f};
    const int fb = tid & 31, il = tid >> 5;
    for (int ic = 0; ic < IND / IPC; ++ic) {
        const int i = ic * IPC + il;
        __syncthreads();
        {
            const uint4 fp = feat_pack(x[(b0 + fb) * IND + i]);
            const int base = fb * (KC / 2) + il * (KPI / 2);
            const int sw = (fb & 7) << 2;
            Fa[(base + 0) ^ sw] = fp.x; Fa[(base + 1) ^ sw] = fp.y;
            Fa[(base + 2) ^ sw] = fp.z; Fa[(base + 3) ^ sw] = fp.w;
            ((ushort*)Fa)[2 * ((base + 4) ^ sw)] = 0;
        }
        {
            const int io = i * OUTD + o0 + fb;
            const float4* cp = reinterpret_cast<const float4*>(coef + (size_t)io * 8);
            const uint4 w = wpack(mask[io], scale_base[io], scale_sp[io], cp[0], cp[1]);
            const int base = fb * (KC / 2) + il * (KPI / 2);
            const int sw = (fb & 7) << 2;
            Wt2[(base + 0) ^ sw] = w.x;
            Wt2[(base + 1) ^ sw] = w.y;
            Wt2[(base + 2) ^ sw] = w.z;
            Wt2[(base + 3) ^ sw] = w.w;
            ((ushort*)Wt2)[2 * ((base + 4) ^ sw)] = 0;
        }
        __syncthreads();
        {
            const ushort* fs = (const ushort*)Fa;
            const ushort* wsd = (const ushort*)Wt2;
            const int ar = wmv + (lane & 15), br = wnv + (lane & 15);
            const int kg = (lane >> 4) * 8;
#pragma unroll
            for (int ksi = 0; ksi < 4; ++ksi) {
                const int ka = ksi * 32 + kg;
                const int ia = (ar * KC + ka) ^ ((ar & 7) << 3);
                const int ib = (br * KC + ka) ^ ((br & 7) << 3);
                bf16x8 a = *reinterpret_cast<const bf16x8*>(fs + ia);
                bf16x8 b = *reinterpret_cast<const bf16x8*>(wsd + ib);
                acc = __builtin_amdgcn_mfma_f32_16x16x32_bf16(a, b, acc, 0, 0, 0);
            }
        }
    }
    const int col = o0 + wnv + (lane & 15);
    const int row0 = b0 + wmv + ((lane >> 4) << 2);
    float bv = 0.f;
    for (int i = 0; i < IND; ++i) {
        const int io = i * OUTD + col;
        bv += mask[io] * scale_sp[io] * coef[(size_t)io * 8 + 7];
    }
#pragma unroll
    for (int rr = 0; rr < 4; ++rr)
        out[(size_t)(row0 + rr) * OUTD + col] = acc[rr] + bv;
}

extern "C" void kernel_launch(void* const* d_in, const int* in_sizes, int n_in,
                              void* d_out, int out_size, void* d_ws, size_t ws_size,
                              hipStream_t stream) {
    const float* x          = (const float*)d_in[0];
    const float* coef       = (const float*)d_in[2];
    const float* scale_base = (const float*)d_in[3];
    const float* scale_sp   = (const float*)d_in[4];
    const float* mask       = (const float*)d_in[5];
    float* out = (float*)d_out;

    hipError_t e = hipFuncSetAttribute(
        (const void*)kan_gemm, hipFuncAttributeMaxDynamicSharedMemorySize, LDSB2);

    if (e == hipSuccess && ws_size >= WS_NEED) {
        uint4* W    = (uint4*)d_ws;
        float* bias = (float*)((char*)d_ws + BIASOFF);
        uint4* F    = (uint4*)((char*)d_ws + FOFF);
        kan_prep<<<512, 256, 0, stream>>>(x, coef, scale_base, scale_sp, mask, W, bias, F);
        kan_gemm<<<256, 512, LDSB2, stream>>>(F, W, bias, out);
    } else {
        kan_mfma<<<dim3(BATCH / 32, OUTD / 32), 256, 0, stream>>>(
            x, coef, scale_base, scale_sp, mask, out);
    }
}